// Round 17
// baseline (238.490 us; speedup 1.0000x reference)
//
#include <hip/hip_runtime.h>
#include <math.h>

#define BB   128
#define TT   64
#define IND  128
#define HID  256
#define CD   384   // comb dim = IND + HID

typedef float v2f __attribute__((ext_vector_type(2)));

struct C2 { float x, y; };
__device__ __forceinline__ C2 cmul(C2 a, C2 b) { return {a.x*b.x - a.y*b.y, a.x*b.y + a.y*b.x}; }
__device__ __forceinline__ C2 cadd(C2 a, C2 b) { return {a.x + b.x, a.y + b.y}; }
__device__ __forceinline__ C2 csub(C2 a, C2 b) { return {a.x - b.x, a.y - b.y}; }
__device__ __forceinline__ C2 conjc(C2 a) { return {a.x, -a.y}; }

__device__ __forceinline__ v2f pk(float a, float b) { v2f r; r.x = a; r.y = b; return r; }
__device__ __forceinline__ v2f swp(v2f v) { return __builtin_shufflevector(v, v, 1, 0); }

struct Args {
    const float* x;
    const float* W[4];
    const float* bb[4];
    const float* qp[4];
    const float* Uo[4];
    const float* cb[4];
    float* out;
};

template<int CTRL>
__device__ __forceinline__ int dppmv(int v) {
    return __builtin_amdgcn_update_dpp(v, v, CTRL, 0xF, 0xF, false);
}

// Lane-xor exchange (R9-R16 proven, all-VALU).
template<int M>
__device__ __forceinline__ float lx(float v) {
    int i = __float_as_int(v);
    if constexpr (M == 1)
        return __int_as_float(dppmv<0xB1>(i));            // quad_perm [1,0,3,2]
    else if constexpr (M == 2)
        return __int_as_float(dppmv<0x4E>(i));            // quad_perm [2,3,0,1]
    else if constexpr (M == 4) {
        int a = dppmv<0x104>(i);                          // row_shl:4
        int b = dppmv<0x114>(i);                          // row_shr:4
        return __int_as_float((threadIdx.x & 4) ? b : a);
    } else if constexpr (M == 8)
        return __int_as_float(dppmv<0x128>(i));           // row_ror:8 == xor8
    else if constexpr (M == 16) {
#if __has_builtin(__builtin_amdgcn_permlane16_swap)
        auto r = __builtin_amdgcn_permlane16_swap(i, i, false, false);
        return __int_as_float((threadIdx.x & 16) ? r[0] : r[1]);
#else
        return __int_as_float(__builtin_amdgcn_ds_swizzle(i, 0x401F));
#endif
    } else {
#if __has_builtin(__builtin_amdgcn_permlane32_swap)
        auto r = __builtin_amdgcn_permlane32_swap(i, i, false, false);
        return __int_as_float((threadIdx.x & 32) ? r[0] : r[1]);
#else
        return __shfl_xor(v, 32);
#endif
    }
}
template<int M>
__device__ __forceinline__ v2f lx2(v2f v) {
    return pk(lx<M>(v.x), lx<M>(v.y));
}

__device__ __forceinline__ float rfl(float v) {
    return __int_as_float(__builtin_amdgcn_readfirstlane(__float_as_int(v)));
}
__device__ __forceinline__ float bcast_lane(float v, int srclane) {
    return __int_as_float(__builtin_amdgcn_readlane(__float_as_int(v), srclane));
}
__device__ __forceinline__ float sigm(float x) {
    return __builtin_amdgcn_rcpf(1.f + __expf(-x));
}
__device__ __forceinline__ float tanh_fast(float x) {
    float e = __expf(2.f * x);
    return 1.f - 2.f * __builtin_amdgcn_rcpf(e + 1.f);
}
__device__ __forceinline__ float sgnx(float v, unsigned m) {
    return __int_as_float(__float_as_int(v) ^ (int)m);
}

// Packed SU(2) lane-gate on both reg-pairs; u0..u3 per-lane scalars.
template<int M>
__device__ __forceinline__ void gate_lane_pk(v2f& xe01, v2f& xi01, v2f& xe23, v2f& xi23,
                                             float u0, float u1, float u2, float u3) {
    v2f px0 = lx2<M>(xe01), py0 = lx2<M>(xi01);
    v2f px2 = lx2<M>(xe23), py2 = lx2<M>(xi23);
    v2f ne0 = u0*xe01 - u1*xi01 + u2*px0 - u3*py0;
    v2f ni0 = u0*xi01 + u1*xe01 + u2*py0 + u3*px0;
    v2f ne2 = u0*xe23 - u1*xi23 + u2*px2 - u3*py2;
    v2f ni2 = u0*xi23 + u1*xe23 + u2*py2 + u3*px2;
    xe01 = ne0; xi01 = ni0; xe23 = ne2; xi23 = ni2;
}

// 512 threads = 8 waves: waves 0-3 -> sample b0 (gates f,i,g,o), waves 4-7 -> sample b0+1.
// Each SIMD hosts 2 waves from INDEPENDENT samples -> HW scheduler fills stall
// cycles with the other sample's instructions (TLP; compiler-ILP refuted R13-R15).
__global__ __launch_bounds__(512, 2) void qlstm_kernel(Args a) {
    const int b0   = blockIdx.x * 2;
    const int tid  = threadIdx.x;
    const int lane = tid & 63;
    const int wv   = tid >> 6;          // 0..7
    const int g    = wv & 3;            // gate id
    const int smp  = wv >> 2;           // sample-in-block
    const int l    = tid & 255;         // per-sample thread id (hidden unit j)
    const int b    = b0 + smp;

    __shared__ float Ax[2][TT][32];                    // x-part of angles per sample
    __shared__ __align__(16) float hH[2][16][HID];     // h history rings
    __shared__ __align__(16) float4 uab[4][2][8];      // SU(2) params (shared by samples)
    __shared__ __align__(16) float expL[2][32];        // <Z_q>, [sample][q*4+gate]

    const int a_ang = l >> 3, p = l & 7;
    const int g_ang = a_ang >> 3, q_ang = a_ang & 7;
    v2f whr2[8][2];
    {
        const float* Wg = a.W[g_ang] + q_ang * CD + IND;
#pragma unroll
        for (int k = 0; k < 8; ++k) {
            int base = p * 32 + ((4 * (k + p)) & 31);
            whr2[k][0] = pk(Wg[base + 0], Wg[base + 1]);
            whr2[k][1] = pk(Wg[base + 2], Wg[base + 3]);
        }
    }
    // output-stage: pack U rows across gate pairs (f,i) and (g,o)
    v2f ur2a[8], ur2b[8], cb2a, cb2b;
#pragma unroll
    for (int k = 0; k < 8; ++k) {
        ur2a[k] = pk(a.Uo[0][l * 8 + k], a.Uo[1][l * 8 + k]);
        ur2b[k] = pk(a.Uo[2][l * 8 + k], a.Uo[3][l * 8 + k]);
    }
    cb2a = pk(a.cb[0][l], a.cb[1][l]);
    cb2b = pk(a.cb[2][l], a.cb[3][l]);

    // ---- SU(2) parameter unitaries alpha,beta = Rz*Ry*Rx (once; shared) ----
    if (tid < 64) {
        int gg = tid >> 4, d = (tid >> 3) & 1, q = tid & 7;
        const float* qp = a.qp[gg] + q * 6 + d * 3;
        float s0, c0, s1, c1, s2, c2;
        sincosf(0.5f * qp[0], &s0, &c0);
        sincosf(0.5f * qp[1], &s1, &c1);
        sincosf(0.5f * qp[2], &s2, &c2);
        C2 aX{c0, 0.f}, bX{0.f, -s0};
        C2 aY{c1, 0.f}, bY{-s1, 0.f};
        C2 aB = csub(cmul(aY, aX), cmul(bY, conjc(bX)));
        C2 bB = cadd(cmul(aY, bX), cmul(bY, conjc(aX)));
        C2 aZ{c2, -s2};
        C2 al = cmul(aZ, aB), be = cmul(aZ, bB);
        uab[gg][d][q] = make_float4(al.x, al.y, be.x, be.y);
    }

    // ---- x-part of angles, both samples, all timesteps (once) ----
    for (int rep = 0; rep < 8; ++rep) {
        int idx = rep * 512 + tid;                     // 4096 = 2 samples x 64t x 32a
        int s = idx >> 11, t = (idx >> 5) & 63, aa = idx & 31;
        int gg = aa >> 3, qq = aa & 7;
        const float4* w4 = (const float4*)(a.W[gg] + qq * CD);
        const float4* x4 = (const float4*)(a.x + (size_t)(t * BB + b0 + s) * IND);
        float acc = a.bb[gg][qq];
        for (int e = 0; e < IND / 4; ++e) {
            float4 xv = x4[e], wvv = w4[e];
            acc += xv.x * wvv.x + xv.y * wvv.y + xv.z * wvv.z + xv.w * wvv.w;
        }
        Ax[s][t][aa] = acc;
    }

    hH[smp][15][l] = 0.f;
    float creg = 0.f, h = 0.f;
    __syncthreads();

    // ---- d=0 unitaries prepacked for the v-build ----
    v2f pA[8], pB[8], pC[8], pD[8];
#pragma unroll
    for (int q = 0; q < 8; ++q) {
        float4 u = uab[g][0][q];
        float ax = rfl(u.x), ay = rfl(u.y), bx = rfl(u.z), by = rfl(u.w);
        pA[q] = pk(ax, -bx);
        pB[q] = pk(by, -ay);
        pC[q] = pk(ay, by);
        pD[q] = pk(-bx, -ax);
    }
    // ---- d=1 lane-gate unitaries, sign-baked per lane ----
    float gA[6][4];
#pragma unroll
    for (int qi = 0; qi < 6; ++qi) {
        float4 u = uab[g][1][qi + 2];
        bool bit = (lane >> (5 - qi)) & 1;
        gA[qi][0] = u.x;
        gA[qi][1] = bit ? -u.y : u.y;
        gA[qi][2] = bit ? -u.z : u.z;
        gA[qi][3] = u.w;
    }
    // ---- d=1 reg-gate unitaries ----
    float q0ax, q0ay, q0bx, q0by;
    float q1ax, q1by;
    v2f q1aym, q1ayp, q1bxm;
    {
        float4 u0 = uab[g][1][0], u1 = uab[g][1][1];
        q0ax = rfl(u0.x); q0ay = rfl(u0.y); q0bx = rfl(u0.z); q0by = rfl(u0.w);
        q1ax = rfl(u1.x); q1by = rfl(u1.w);
        float ay = rfl(u1.y), bx = rfl(u1.z);
        q1aym = pk(-ay, ay);
        q1ayp = pk(ay, -ay);
        q1bxm = pk(bx, -bx);
    }

    // ---- d=0 CNOT fold selectors (proven R11) ----
    const bool st3 = ((lane >> 4) ^ (lane >> 5)) & 1;
    const bool st4 = ((lane >> 3) ^ (lane >> 4)) & 1;
    const bool st5 = ((lane >> 2) ^ (lane >> 3)) & 1;
    const bool st6 = ((lane >> 1) ^ (lane >> 2)) & 1;
    const bool st7 = (lane ^ (lane >> 1)) & 1;
    const bool sp2 = (lane >> 5) & 1;
    const bool sp7 = lane & 1;

    // ---- measurement sign masks (proven R10) ----
    unsigned sg0, sg2, sg3, sg4, sg5, sg6, sg7;
    {
        auto par31 = [](int v) -> unsigned { return (unsigned)(__popc(v) & 1) << 31; };
        sg0 = par31(lane & 63);
        sg2 = par31(lane & 32);
        sg3 = par31(lane & 48);
        sg4 = par31(lane & 56);
        sg5 = par31(lane & 60);
        sg6 = par31(lane & 62);
        sg7 = sg0;
    }

    for (int t = 0; t < TT; ++t) {
        // ---- angle stage (packed dot) ----
        const int rowPrev = (t + 15) & 15;
        const float* hrow = hH[smp][rowPrev];
        v2f acc2 = pk(0.f, 0.f);
#pragma unroll
        for (int k = 0; k < 8; ++k) {
            int base = p * 32 + ((4 * (k + p)) & 31);
            const float4 hv = *reinterpret_cast<const float4*>(&hrow[base]);
            acc2 = acc2 + pk(hv.x, hv.y) * whr2[k][0] + pk(hv.z, hv.w) * whr2[k][1];
        }
        float acc = acc2.x + acc2.y;
        acc += lx<1>(acc);
        acc += lx<2>(acc);
        acc += lx<4>(acc);
        float ang = 0.5f * (acc + Ax[smp][t][a_ang]);
        float cA = __cosf(ang), sA = __sinf(ang);
        float cs_c[8], cs_s[8];
#pragma unroll
        for (int q = 0; q < 8; ++q) {
            cs_c[q] = bcast_lane(cA, q * 8);
            cs_s[q] = bcast_lane(sA, q * 8);
        }

        // ---- packed v-build: Vx[q]=(v0x,v1x), Vy[q]=(v0y,v1y) ----
        v2f Vx[8], Vy[8];
#pragma unroll
        for (int q = 0; q < 8; ++q) {
            Vx[q] = pA[q] * cs_c[q] + pB[q] * cs_s[q];
            Vy[q] = pC[q] * cs_c[q] + pD[q] * cs_s[q];
        }

        // ---- init product at M^-1(p) (d=0 CNOT folded) ----
        v2f xe01, xi01, xe23, xi23;
        {
            C2 f3{ st3 ? Vx[3].y : Vx[3].x, st3 ? Vy[3].y : Vy[3].x };
            C2 f4{ st4 ? Vx[4].y : Vx[4].x, st4 ? Vy[4].y : Vy[4].x };
            C2 f5{ st5 ? Vx[5].y : Vx[5].x, st5 ? Vy[5].y : Vy[5].x };
            C2 f6{ st6 ? Vx[6].y : Vx[6].x, st6 ? Vy[6].y : Vy[6].x };
            C2 f7{ st7 ? Vx[7].y : Vx[7].x, st7 ? Vy[7].y : Vy[7].x };
            C2 c5 = cmul(cmul(cmul(f3, f4), cmul(f5, f6)), f7);
            v2f f2re = sp2 ? swp(Vx[2]) : Vx[2];
            v2f f2im = sp2 ? swp(Vy[2]) : Vy[2];
            v2f c2re = c5.x * f2re - c5.y * f2im;
            v2f c2im = c5.x * f2im + c5.y * f2re;
            v2f f1re = sp7 ? swp(Vx[1]) : Vx[1];
            v2f f1im = sp7 ? swp(Vy[1]) : Vy[1];
            float f0ax = sp7 ? Vx[0].y : Vx[0].x, f0ay = sp7 ? Vy[0].y : Vy[0].x;
            float f0bx = sp7 ? Vx[0].x : Vx[0].y, f0by = sp7 ? Vy[0].x : Vy[0].y;
            v2f uure = f1re * f0ax - f1im * f0ay;
            v2f uuim = f1re * f0ay + f1im * f0ax;
            v2f s1re = swp(f1re), s1im = swp(f1im);
            v2f wwre = s1re * f0bx - s1im * f0by;
            v2f wwim = s1re * f0by + s1im * f0bx;
            xe01 = c2re * uure - c2im * uuim;
            xi01 = c2re * uuim + c2im * uure;
            xe23 = c2re * wwre - c2im * wwim;
            xi23 = c2re * wwim + c2im * wwre;
        }

        // ---- d=1 reg-gates (packed) ----
        {
            v2f ne01 = q0ax*xe01 - q0ay*xi01 + q0bx*xe23 - q0by*xi23;
            v2f ni01 = q0ax*xi01 + q0ay*xe01 + q0bx*xi23 + q0by*xe23;
            v2f ne23 = -q0bx*xe01 - q0by*xi01 + q0ax*xe23 + q0ay*xi23;
            v2f ni23 = -q0bx*xi01 + q0by*xe01 + q0ax*xi23 - q0ay*xe23;
            xe01 = ne01; xi01 = ni01; xe23 = ne23; xi23 = ni23;
        }
        {
            v2f se01 = swp(xe01), si01 = swp(xi01);
            v2f se23 = swp(xe23), si23 = swp(xi23);
            v2f ne01 = q1ax*xe01 + q1aym*xi01 + q1bxm*se01 - q1by*si01;
            v2f ni01 = q1ax*xi01 + q1ayp*xe01 + q1bxm*si01 + q1by*se01;
            v2f ne23 = q1ax*xe23 + q1aym*xi23 + q1bxm*se23 - q1by*si23;
            v2f ni23 = q1ax*xi23 + q1ayp*xe23 + q1bxm*si23 + q1by*se23;
            xe01 = ne01; xi01 = ni01; xe23 = ne23; xi23 = ni23;
        }
        // ---- d=1 lane-gates (packed) ----
        gate_lane_pk<32>(xe01, xi01, xe23, xi23, gA[0][0], gA[0][1], gA[0][2], gA[0][3]);
        gate_lane_pk<16>(xe01, xi01, xe23, xi23, gA[1][0], gA[1][1], gA[1][2], gA[1][3]);
        gate_lane_pk< 8>(xe01, xi01, xe23, xi23, gA[2][0], gA[2][1], gA[2][2], gA[2][3]);
        gate_lane_pk< 4>(xe01, xi01, xe23, xi23, gA[3][0], gA[3][1], gA[3][2], gA[3][3]);
        gate_lane_pk< 2>(xe01, xi01, xe23, xi23, gA[4][0], gA[4][1], gA[4][2], gA[4][3]);
        gate_lane_pk< 1>(xe01, xi01, xe23, xi23, gA[5][0], gA[5][1], gA[5][2], gA[5][3]);

        // ---- expvals: sign masks + full butterfly (packed adds) ----
        v2f pr01 = xe01 * xe01 + xi01 * xi01;
        v2f pr23 = xe23 * xe23 + xi23 * xi23;
        float pr0 = pr01.x, pr1 = pr01.y, pr2 = pr23.x, pr3 = pr23.y;
        float Bc = pr0 - pr1 + pr2 - pr3;
        float Dc = pr0 - pr1 - pr2 + pr3;
        v2f zA = pk(sgnx(Bc, sg0), Dc);
        v2f zB = pk(sgnx(Dc, sg2), sgnx(Dc, sg3));
        v2f zC = pk(sgnx(Dc, sg4), sgnx(Dc, sg5));
        v2f zD = pk(sgnx(Dc, sg6), sgnx(Dc, sg7));
        zA = zA + lx2<1>(zA);  zB = zB + lx2<1>(zB);  zC = zC + lx2<1>(zC);  zD = zD + lx2<1>(zD);
        zA = zA + lx2<2>(zA);  zB = zB + lx2<2>(zB);  zC = zC + lx2<2>(zC);  zD = zD + lx2<2>(zD);
        zA = zA + lx2<4>(zA);  zB = zB + lx2<4>(zB);  zC = zC + lx2<4>(zC);  zD = zD + lx2<4>(zD);
        zA = zA + lx2<8>(zA);  zB = zB + lx2<8>(zB);  zC = zC + lx2<8>(zC);  zD = zD + lx2<8>(zD);
        zA = zA + lx2<16>(zA); zB = zB + lx2<16>(zB); zC = zC + lx2<16>(zC); zD = zD + lx2<16>(zD);
        zA = zA + lx2<32>(zA); zB = zB + lx2<32>(zB); zC = zC + lx2<32>(zC); zD = zD + lx2<32>(zD);
        if (lane == 0) {
            expL[smp][0*4 + g] = zA.x; expL[smp][1*4 + g] = zA.y;
            expL[smp][2*4 + g] = zB.x; expL[smp][3*4 + g] = zB.y;
            expL[smp][4*4 + g] = zC.x; expL[smp][5*4 + g] = zC.y;
            expL[smp][6*4 + g] = zD.x; expL[smp][7*4 + g] = zD.y;
        }
        __syncthreads();

        // ---- output projection (packed across gate pairs) + LSTM pointwise ----
        const float4* eL4 = (const float4*)expL[smp];
        v2f og2a = cb2a, og2b = cb2b;
#pragma unroll
        for (int k = 0; k < 8; ++k) {
            float4 e4 = eL4[k];
            og2a = og2a + pk(e4.x, e4.y) * ur2a[k];
            og2b = og2b + pk(e4.z, e4.w) * ur2b[k];
        }
        float fg = sigm(og2a.x);
        float ig = sigm(og2a.y);
        float gg = tanh_fast(og2b.x);
        float oo = sigm(og2b.y);
        creg = fg * creg + ig * gg;
        h = oo * tanh_fast(creg);

        hH[smp][t & 15][l] = h;
        if ((t & 15) == 15) {
            int t0 = t - 15;
#pragma unroll
            for (int r = 0; r < 16; ++r)
                a.out[(size_t)((t0 + r) * BB + b) * HID + l] = hH[smp][r][l];
        }
        __syncthreads();
    }

    a.out[(size_t)TT * BB * HID + (size_t)b * HID + l] = h;
    a.out[(size_t)TT * BB * HID + (size_t)BB * HID + (size_t)b * HID + l] = creg;
}

extern "C" void kernel_launch(void* const* d_in, const int* in_sizes, int n_in,
                              void* d_out, int out_size, void* d_ws, size_t ws_size,
                              hipStream_t stream) {
    (void)in_sizes; (void)n_in; (void)out_size; (void)d_ws; (void)ws_size;
    Args ar;
    ar.x = (const float*)d_in[0];
    for (int g = 0; g < 4; ++g) {
        ar.W[g]  = (const float*)d_in[1 + 5 * g];
        ar.bb[g] = (const float*)d_in[2 + 5 * g];
        ar.qp[g] = (const float*)d_in[3 + 5 * g];
        ar.Uo[g] = (const float*)d_in[4 + 5 * g];
        ar.cb[g] = (const float*)d_in[5 + 5 * g];
    }
    ar.out = (float*)d_out;
    qlstm_kernel<<<dim3(BB / 2), dim3(512), 0, stream>>>(ar);
}